// Round 3
// baseline (430.166 us; speedup 1.0000x reference)
//
#include <hip/hip_runtime.h>

// MotherCubeConv: out[n,:] = concat(features[n,:], prev[idx[n,0..3],:]) @ W^T + b
// Gathered GEMM [200000 x 640] x [640 x 128] via bf16 MFMA, 3-term hi/lo split:
//   A*W ~= A_hi*W_hi + A_lo*W_hi + A_hi*W_lo   (error ~1e-5 absmax, tol 7.8e-3)
// v3: latency-bound fix. 32 rows x 128 cols per wave (acc=64 regs -> 3 waves/SIMD),
// per-lane-contiguous k-map (lane reads 256B/segment), 1-chunk A prefetch,
// nontemporal C stores. No LDS, no barriers.

#define N_PTS  200000
#define F_INN  128
#define K_TOT  640      // 5 * F_IN
#define NCT    4        // 128 cols / 32

typedef __attribute__((ext_vector_type(8)))  short bf16x8;   // MFMA A/B operand
typedef __attribute__((ext_vector_type(16))) float f32x16;   // MFMA C/D (32x32)
typedef __attribute__((ext_vector_type(8)))  float f32x8;

union Frag { bf16x8 v; unsigned int u[4]; };

__device__ __forceinline__ unsigned int bf_rne_bits(float f) {
    unsigned int u = __builtin_bit_cast(unsigned int, f);
    return (u + 0x7FFFu + ((u >> 16) & 1u)) & 0xFFFF0000u;  // fp32 bits of RNE-bf16
}

// RNE split — W only (runs once over 80 KB)
__device__ __forceinline__ void split8_rne(const f32x8 a, bf16x8& hi, bf16x8& lo) {
    Frag H, L;
#pragma unroll
    for (int p = 0; p < 4; ++p) {
        float f0 = a[2 * p], f1 = a[2 * p + 1];
        unsigned int h0 = bf_rne_bits(f0), h1 = bf_rne_bits(f1);
        float r0 = f0 - __builtin_bit_cast(float, h0);
        float r1 = f1 - __builtin_bit_cast(float, h1);
        unsigned int l0 = bf_rne_bits(r0), l1 = bf_rne_bits(r1);
        H.u[p] = (h0 >> 16) | h1;
        L.u[p] = (l0 >> 16) | l1;
    }
    hi = H.v; lo = L.v;
}

// Truncation split — A hot path (~10 VALU / f32 pair)
__device__ __forceinline__ void split8_trunc(const f32x8 a, bf16x8& hi, bf16x8& lo) {
    Frag H, L;
#pragma unroll
    for (int p = 0; p < 4; ++p) {
        float f0 = a[2 * p], f1 = a[2 * p + 1];
        unsigned int u0 = __builtin_bit_cast(unsigned int, f0);
        unsigned int u1 = __builtin_bit_cast(unsigned int, f1);
        unsigned int h0 = u0 & 0xFFFF0000u, h1 = u1 & 0xFFFF0000u;
        float r0 = f0 - __builtin_bit_cast(float, h0);
        float r1 = f1 - __builtin_bit_cast(float, h1);
        unsigned int l0 = __builtin_bit_cast(unsigned int, r0);
        unsigned int l1 = __builtin_bit_cast(unsigned int, r1);
        H.u[p] = (h0 >> 16) | h1;
        L.u[p] = (l0 >> 16) | (l1 & 0xFFFF0000u);
    }
    hi = H.v; lo = L.v;
}

// k-map (must match between A and W fragments; MFMA is invariant to the
// per-chunk k-bijection as long as both operands use the same one):
//   chunk t = s*8+cc, slot (g=lane>>5, j=0..7)  ->  k = s*128 + g*64 + cc*8 + j
// so each lane's A data per segment is one contiguous 256B run [g*64, g*64+64).
__global__ void build_wf(const float* __restrict__ W,
                         bf16x8* __restrict__ wf_hi,
                         bf16x8* __restrict__ wf_lo) {
    int tid = blockIdx.x * blockDim.x + threadIdx.x;  // (t*4+ct)*64 + lane
    int lane = tid & 63;
    int ct   = (tid >> 6) & 3;
    int t    = tid >> 8;
    if (t >= 40) return;
    int s  = t >> 3, cc = t & 7;
    int g  = lane >> 5, r31 = lane & 31;
    int c  = ct * 32 + r31;
    int kk = s * 128 + g * 64 + cc * 8;
    f32x8 w = *(const f32x8*)(W + (size_t)c * K_TOT + kk);
    bf16x8 h, l;
    split8_rne(w, h, l);
    wf_hi[tid] = h;
    wf_lo[tid] = l;
}

__global__ __launch_bounds__(256, 3)
void mcconv(const float* __restrict__ feat, const float* __restrict__ prev,
            const int* __restrict__ nbr, const float* __restrict__ bias,
            const bf16x8* __restrict__ wf_hi, const bf16x8* __restrict__ wf_lo,
            float* __restrict__ out) {
    const int lane = threadIdx.x & 63;
    const int wave = threadIdx.x >> 6;
    const int g    = lane >> 5;     // k-half
    const int r31  = lane & 31;
    const int n0   = blockIdx.x * 128 + wave * 32;   // wave's 32 rows

    int nA  = n0 + r31;
    int nAc = nA < N_PTS ? nA : N_PTS - 1;
    const int4 iA = *(const int4*)(nbr + 4 * (size_t)nAc);

    // segment base pointers (per-lane), each row read at [g*64, g*64+64)
    const float* p0 = feat + (size_t)nAc  * F_INN + g * 64;
    const float* p1 = prev + (size_t)iA.x * F_INN + g * 64;
    const float* p2 = prev + (size_t)iA.y * F_INN + g * 64;
    const float* p3 = prev + (size_t)iA.z * F_INN + g * 64;
    const float* p4 = prev + (size_t)iA.w * F_INN + g * 64;

    f32x16 acc[NCT];
#pragma unroll
    for (int c = 0; c < NCT; ++c)
#pragma unroll
        for (int i = 0; i < 16; ++i) acc[c][i] = 0.0f;

    f32x8 a_cur = *(const f32x8*)p0;   // segment 0, chunk 0

    // one segment: 8 chunks of k=16; prefetches chunk+1 (or pnext chunk 0)
    auto SEG = [&](int sbase, const float* p, const float* pnext) {
#pragma unroll
        for (int cc = 0; cc < 8; ++cc) {
            const int t = sbase + cc;
            // next A chunk (prefetch)
            f32x8 a_next = (cc < 7) ? *(const f32x8*)(p + (cc + 1) * 8)
                                    : *(const f32x8*)pnext;
            // W fragments for this chunk
            bf16x8 bh[NCT], bl[NCT];
#pragma unroll
            for (int ct = 0; ct < NCT; ++ct) {
                int fi = (t * 4 + ct) * 64 + lane;
                bh[ct] = wf_hi[fi];
                bl[ct] = wf_lo[fi];
            }
            bf16x8 ah, al;
            split8_trunc(a_cur, ah, al);
#pragma unroll
            for (int ct = 0; ct < NCT; ++ct) {
                acc[ct] = __builtin_amdgcn_mfma_f32_32x32x16_bf16(ah, bh[ct], acc[ct], 0, 0, 0);
                acc[ct] = __builtin_amdgcn_mfma_f32_32x32x16_bf16(al, bh[ct], acc[ct], 0, 0, 0);
                acc[ct] = __builtin_amdgcn_mfma_f32_32x32x16_bf16(ah, bl[ct], acc[ct], 0, 0, 0);
            }
            a_cur = a_next;
        }
    };

    SEG(0,  p0, p1);
    SEG(8,  p1, p2);
    SEG(16, p2, p3);
    SEG(24, p3, p4);
    SEG(32, p4, p4);   // last prefetch is a harmless re-read

    // epilogue: bias + nontemporal store.
    // C/D layout (m74/m101): col = lane&31, row = (reg&3)+8*(reg>>2)+4*(lane>>5)
    float bcol[NCT];
#pragma unroll
    for (int ct = 0; ct < NCT; ++ct) bcol[ct] = bias[ct * 32 + r31];

#pragma unroll
    for (int reg = 0; reg < 16; ++reg) {
        const int row = n0 + (reg & 3) + 8 * (reg >> 2) + 4 * g;
        if (row < N_PTS) {
#pragma unroll
            for (int ct = 0; ct < NCT; ++ct)
                __builtin_nontemporal_store(acc[ct][reg] + bcol[ct],
                                            out + (size_t)row * F_INN + ct * 32 + r31);
        }
    }
}

extern "C" void kernel_launch(void* const* d_in, const int* in_sizes, int n_in,
                              void* d_out, int out_size, void* d_ws, size_t ws_size,
                              hipStream_t stream) {
    const float* feat = (const float*)d_in[0];
    const float* prev = (const float*)d_in[1];
    const int*   nbr  = (const int*)d_in[2];
    const float* W    = (const float*)d_in[3];
    const float* bias = (const float*)d_in[4];
    float* out = (float*)d_out;

    bf16x8* wf_hi = (bf16x8*)d_ws;                       // 160 KiB
    bf16x8* wf_lo = (bf16x8*)((char*)d_ws + (size_t)40 * NCT * 64 * sizeof(bf16x8));

    hipLaunchKernelGGL(build_wf, dim3(40), dim3(256), 0, stream, W, wf_hi, wf_lo);

    const int grid = (N_PTS + 127) / 128;   // 1563 blocks, 4 waves x 32 rows
    hipLaunchKernelGGL(mcconv, dim3(grid), dim3(256), 0, stream,
                       feat, prev, nbr, bias, wf_hi, wf_lo, out);
}

// Round 4
// 338.290 us; speedup vs baseline: 1.2716x; 1.2716x over previous
//
#include <hip/hip_runtime.h>

// MotherCubeConv: out[n,:] = concat(features[n,:], prev[idx[n,0..3],:]) @ W^T + b
// Gathered GEMM [200000 x 640] x [640 x 128] via bf16 MFMA, 3-term hi/lo split:
//   A*W ~= A_hi*W_hi + A_lo*W_hi + A_hi*W_lo   (error ~1e-5, tol 7.8e-3)
// v4: W fragments staged in LDS (double-buffered, global_load_lds w=16),
// shared by the block's 4 waves -> kills the per-wave L2 wf re-fetch latency
// that capped rounds 2/3 at 14-18% MfmaUtil. 4 waves x 64 rows (2 m-tiles),
// 10 phases x (stage 32KB | compute 4 chunks of k=16), 1 barrier/phase.

#define N_PTS  200000
#define F_INN  128
#define K_TOT  640      // 5 * F_IN
#define NCT    4        // 128 cols / 32

typedef __attribute__((ext_vector_type(8)))  short bf16x8;   // MFMA A/B operand
typedef __attribute__((ext_vector_type(16))) float f32x16;   // MFMA C/D (32x32)
typedef __attribute__((ext_vector_type(8)))  float f32x8;

union Frag { bf16x8 v; unsigned int u[4]; };

__device__ __forceinline__ unsigned int bf_rne_bits(float f) {
    unsigned int u = __builtin_bit_cast(unsigned int, f);
    return (u + 0x7FFFu + ((u >> 16) & 1u)) & 0xFFFF0000u;  // fp32 bits of RNE-bf16
}

// RNE split — W only (runs once over 80 KB)
__device__ __forceinline__ void split8_rne(const f32x8 a, bf16x8& hi, bf16x8& lo) {
    Frag H, L;
#pragma unroll
    for (int p = 0; p < 4; ++p) {
        float f0 = a[2 * p], f1 = a[2 * p + 1];
        unsigned int h0 = bf_rne_bits(f0), h1 = bf_rne_bits(f1);
        float r0 = f0 - __builtin_bit_cast(float, h0);
        float r1 = f1 - __builtin_bit_cast(float, h1);
        unsigned int l0 = bf_rne_bits(r0), l1 = bf_rne_bits(r1);
        H.u[p] = (h0 >> 16) | h1;
        L.u[p] = (l0 >> 16) | l1;
    }
    hi = H.v; lo = L.v;
}

// Truncation split — A hot path (~10 VALU / f32 pair)
__device__ __forceinline__ void split8_trunc(const f32x8 a, bf16x8& hi, bf16x8& lo) {
    Frag H, L;
#pragma unroll
    for (int p = 0; p < 4; ++p) {
        float f0 = a[2 * p], f1 = a[2 * p + 1];
        unsigned int u0 = __builtin_bit_cast(unsigned int, f0);
        unsigned int u1 = __builtin_bit_cast(unsigned int, f1);
        unsigned int h0 = u0 & 0xFFFF0000u, h1 = u1 & 0xFFFF0000u;
        float r0 = f0 - __builtin_bit_cast(float, h0);
        float r1 = f1 - __builtin_bit_cast(float, h1);
        unsigned int l0 = __builtin_bit_cast(unsigned int, r0);
        unsigned int l1 = __builtin_bit_cast(unsigned int, r1);
        H.u[p] = (h0 >> 16) | h1;
        L.u[p] = (l0 >> 16) | (l1 & 0xFFFF0000u);
    }
    hi = H.v; lo = L.v;
}

// Pre-kernel: W [128 x 640] fp32 -> fragment-ready bf16 hi/lo, INTERLEAVED so
// each k-chunk is one contiguous 8 KB block (4 ct x {hi,lo} x 64 lanes x 16B):
//   byte offset of frag(t, ct, h, lane) = ((t*4 + ct)*2 + h)*1024 + lane*16
// k-map (round-2, must match A loads): c = ct*32+(lane&31), k = t*16+(lane>>5)*8+j
__global__ void build_wf(const float* __restrict__ W, bf16x8* __restrict__ wfbuf) {
    int tid = blockIdx.x * blockDim.x + threadIdx.x;
    int lane = tid & 63;
    int ct   = (tid >> 6) & 3;
    int t    = tid >> 8;
    if (t >= 40) return;
    int c = ct * 32 + (lane & 31);
    int k = t * 16 + (lane >> 5) * 8;
    f32x8 w = *(const f32x8*)(W + (size_t)c * K_TOT + k);
    bf16x8 h, l;
    split8_rne(w, h, l);
    wfbuf[((t * 4 + ct) * 2 + 0) * 64 + lane] = h;
    wfbuf[((t * 4 + ct) * 2 + 1) * 64 + lane] = l;
}

__global__ __launch_bounds__(256, 2)
void mcconv(const float* __restrict__ feat, const float* __restrict__ prev,
            const int* __restrict__ nbr, const float* __restrict__ bias,
            const char* __restrict__ wfbuf, float* __restrict__ out) {
    __shared__ char smem[2 * 32768];   // double-buffered: one phase = 4 chunks = 32 KB

    const int lane = threadIdx.x & 63;
    const int wave = threadIdx.x >> 6;
    const int g    = lane >> 5;     // k-half
    const int r31  = lane & 31;
    const int n0   = blockIdx.x * 256 + wave * 64;

    int nA  = n0 + r31;
    int nB  = n0 + 32 + r31;
    int nAc = nA < N_PTS ? nA : N_PTS - 1;
    int nBc = nB < N_PTS ? nB : N_PTS - 1;
    const int4 iA = *(const int4*)(nbr + 4 * (size_t)nAc);
    const int4 iB = *(const int4*)(nbr + 4 * (size_t)nBc);

    // per-segment row pointers (named vars, no runtime-indexed array -> no scratch)
    const float* s0A = feat + (size_t)nAc  * F_INN;
    const float* s0B = feat + (size_t)nBc  * F_INN;
    const float* s1A = prev + (size_t)iA.x * F_INN;
    const float* s1B = prev + (size_t)iB.x * F_INN;
    const float* s2A = prev + (size_t)iA.y * F_INN;
    const float* s2B = prev + (size_t)iB.y * F_INN;
    const float* s3A = prev + (size_t)iA.z * F_INN;
    const float* s3B = prev + (size_t)iB.z * F_INN;
    const float* s4A = prev + (size_t)iA.w * F_INN;
    const float* s4B = prev + (size_t)iB.w * F_INN;

    f32x16 acc[2][NCT];
#pragma unroll
    for (int m = 0; m < 2; ++m)
#pragma unroll
        for (int c = 0; c < NCT; ++c)
#pragma unroll
            for (int i = 0; i < 16; ++i) acc[m][c][i] = 0.0f;

    // stage one 32 KB phase: each wave copies its 8 KB quarter as 8 x 1 KB
    // global_load_lds (LDS dest = wave-uniform base + lane*16 -> linear, matches
    // the linear wfbuf layout).
    auto STAGE = [&](int buf, int phase) {
        const char* gsrc = wfbuf + (size_t)phase * 32768 + wave * 8192 + lane * 16;
        char* ldst = smem + buf * 32768 + wave * 8192;
#pragma unroll
        for (int i = 0; i < 8; ++i) {
            __builtin_amdgcn_global_load_lds(
                (const __attribute__((address_space(1))) unsigned int*)(gsrc + i * 1024),
                (__attribute__((address_space(3))) unsigned int*)(ldst + i * 1024),
                16, 0, 0);
        }
    };

    STAGE(0, 0);
    __syncthreads();   // compiler emits vmcnt(0) drain before s_barrier

    for (int p = 0; p < 10; ++p) {
        const int cur = p & 1;
        if (p < 9) STAGE(cur ^ 1, p + 1);   // prefetch next phase into other buffer

        const int s   = p >> 1;        // segment (2 phases per 128-float segment)
        const int cc0 = (p & 1) * 4;   // first chunk-in-segment of this phase
        const float *pA, *pB;
        if      (s == 0) { pA = s0A; pB = s0B; }
        else if (s == 1) { pA = s1A; pB = s1B; }
        else if (s == 2) { pA = s2A; pB = s2B; }
        else if (s == 3) { pA = s3A; pB = s3B; }
        else             { pA = s4A; pB = s4B; }

        const char* fb = smem + cur * 32768;
#pragma unroll
        for (int c = 0; c < 4; ++c) {
            const int cc = cc0 + c;
            f32x8 aA = *(const f32x8*)(pA + cc * 16 + g * 8);
            f32x8 aB = *(const f32x8*)(pB + cc * 16 + g * 8);
            bf16x8 ahA, alA, ahB, alB;
            split8_trunc(aA, ahA, alA);
            split8_trunc(aB, ahB, alB);
#pragma unroll
            for (int ct = 0; ct < NCT; ++ct) {
                bf16x8 bh = *(const bf16x8*)(fb + c * 8192 + ct * 2048 +        lane * 16);
                bf16x8 bl = *(const bf16x8*)(fb + c * 8192 + ct * 2048 + 1024 + lane * 16);
                acc[0][ct] = __builtin_amdgcn_mfma_f32_32x32x16_bf16(ahA, bh, acc[0][ct], 0, 0, 0);
                acc[0][ct] = __builtin_amdgcn_mfma_f32_32x32x16_bf16(alA, bh, acc[0][ct], 0, 0, 0);
                acc[0][ct] = __builtin_amdgcn_mfma_f32_32x32x16_bf16(ahA, bl, acc[0][ct], 0, 0, 0);
                acc[1][ct] = __builtin_amdgcn_mfma_f32_32x32x16_bf16(ahB, bh, acc[1][ct], 0, 0, 0);
                acc[1][ct] = __builtin_amdgcn_mfma_f32_32x32x16_bf16(alB, bh, acc[1][ct], 0, 0, 0);
                acc[1][ct] = __builtin_amdgcn_mfma_f32_32x32x16_bf16(ahB, bl, acc[1][ct], 0, 0, 0);
            }
        }
        __syncthreads();   // staged data for p+1 landed; all reads of cur done
    }

    // epilogue: bias + store. C/D layout (m74/m101): col = lane&31,
    // row = (reg&3) + 8*(reg>>2) + 4*(lane>>5)
    float bcol[NCT];
#pragma unroll
    for (int ct = 0; ct < NCT; ++ct) bcol[ct] = bias[ct * 32 + r31];

#pragma unroll
    for (int m = 0; m < 2; ++m) {
        const int nbase = n0 + m * 32 + 4 * g;
#pragma unroll
        for (int reg = 0; reg < 16; ++reg) {
            const int row = nbase + (reg & 3) + 8 * (reg >> 2);
            if (row < N_PTS) {
#pragma unroll
                for (int ct = 0; ct < NCT; ++ct)
                    out[(size_t)row * F_INN + ct * 32 + r31] = acc[m][ct][reg] + bcol[ct];
            }
        }
    }
}

extern "C" void kernel_launch(void* const* d_in, const int* in_sizes, int n_in,
                              void* d_out, int out_size, void* d_ws, size_t ws_size,
                              hipStream_t stream) {
    const float* feat = (const float*)d_in[0];
    const float* prev = (const float*)d_in[1];
    const int*   nbr  = (const int*)d_in[2];
    const float* W    = (const float*)d_in[3];
    const float* bias = (const float*)d_in[4];
    float* out = (float*)d_out;

    bf16x8* wfbuf = (bf16x8*)d_ws;   // 320 KiB, phase-contiguous

    hipLaunchKernelGGL(build_wf, dim3(40), dim3(256), 0, stream, W, wfbuf);

    const int grid = (N_PTS + 255) / 256;   // 782 blocks, 4 waves x 64 rows
    hipLaunchKernelGGL(mcconv, dim3(grid), dim3(256), 0, stream,
                       feat, prev, nbr, bias, (const char*)wfbuf, out);
}